// Round 8
// baseline (60.550 us; speedup 1.0000x reference)
//
#include <hip/hip_runtime.h>
#include <hip/hip_cooperative_groups.h>

namespace cg = cooperative_groups;

// Sinkhorn top-K — closed-form scalar root-find, single cooperative kernel.
//   q[n]   = exp2((2 s[n] - 1) * C1f / Cmax)
//   S(rho) = sum_n 1/(1 + rho q[n]) = K    (monotone decreasing, convex)
//   P0[n]  = (1/N)/(1 + rho q[n]);  P1[n] = (1/N) rho q[n]/(1 + rho q[n])
// Phase 1: each block row-maxes the cost from its own registers -> ws[b].
// grid.sync. Phase 2: reduce 512 partials -> Cmax (exact max, grouping-
// invariant), build q, guarded-Halley root-find (2-cycle-safe), store P.

#define EXP2(x) __builtin_amdgcn_exp2f(x)
#define RCP(x)  __builtin_amdgcn_rcpf(x)

constexpr int B = 512;
constexpr int N = 2048;
constexpr int TPB = 256;
constexpr int EPT = N / TPB; // 8 elements per thread
constexpr int IT_MAX = 16;

#define C1f   14.426950408889634f     // log2(e)/EPS
#define KF    512.0f
#define INV_N (1.0f / 2048.0f)

template <int CTRL, int RM>
__device__ __forceinline__ int DPP(int v) {
    return __builtin_amdgcn_update_dpp(0, v, CTRL, RM, 0xf, false);
}

// wave64 max all-reduce (values >= 0) -> uniform in all lanes.
__device__ __forceinline__ float wave_max_bcast(float v) {
    float t;
    t = __int_as_float(DPP<0x111, 0xf>(__float_as_int(v))); v = fmaxf(v, t);
    t = __int_as_float(DPP<0x112, 0xf>(__float_as_int(v))); v = fmaxf(v, t);
    t = __int_as_float(DPP<0x114, 0xf>(__float_as_int(v))); v = fmaxf(v, t);
    t = __int_as_float(DPP<0x118, 0xf>(__float_as_int(v))); v = fmaxf(v, t);
    t = __int_as_float(DPP<0x142, 0xa>(__float_as_int(v))); v = fmaxf(v, t); // row_bcast15
    t = __int_as_float(DPP<0x143, 0xc>(__float_as_int(v))); v = fmaxf(v, t); // row_bcast31
    return __int_as_float(__builtin_amdgcn_readlane(__float_as_int(v), 63));
}

// three interleaved wave64 sum all-reduces (latency-overlapped DPP chains)
__device__ __forceinline__ void wave_sum3_bcast(float& a, float& b, float& c) {
#define R3(ctrl, rm)                                          \
    {                                                         \
        int ta = DPP<ctrl, rm>(__float_as_int(a));            \
        int tb = DPP<ctrl, rm>(__float_as_int(b));            \
        int tc = DPP<ctrl, rm>(__float_as_int(c));            \
        a += __int_as_float(ta);                              \
        b += __int_as_float(tb);                              \
        c += __int_as_float(tc);                              \
    }
    R3(0x111, 0xf) R3(0x112, 0xf) R3(0x114, 0xf) R3(0x118, 0xf)
    R3(0x142, 0xa) R3(0x143, 0xc)
#undef R3
    a = __int_as_float(__builtin_amdgcn_readlane(__float_as_int(a), 63));
    b = __int_as_float(__builtin_amdgcn_readlane(__float_as_int(b), 63));
    c = __int_as_float(__builtin_amdgcn_readlane(__float_as_int(c), 63));
}

__launch_bounds__(TPB)
__global__ void k_fused(const float* __restrict__ scores,
                        float* __restrict__ ws,
                        float* __restrict__ out) {
    const int b = blockIdx.x;
    const int t = threadIdx.x;
    const int lane = t & 63, wid = t >> 6;

    __shared__ float redRow[4];
    __shared__ float redC[4];
    __shared__ alignas(16) float lred[2][3][4]; // [parity][S/D/H][wave]

    // --- load this row: two coalesced float4s per thread ---
    const float4* src = (const float4*)(scores + b * N);
    float4 va = src[t], vb = src[t + TPB];

    // --- per-row cost max: max(s^2, (s-1)^2) over 8 elements ---
    float m;
    {
        float a0 = fmaxf(fmaxf(va.x * va.x, va.y * va.y), fmaxf(va.z * va.z, va.w * va.w));
        float a1 = fmaxf(fmaxf(vb.x * vb.x, vb.y * vb.y), fmaxf(vb.z * vb.z, vb.w * vb.w));
        float cx = va.x - 1.f, cy = va.y - 1.f, cz = va.z - 1.f, cw = va.w - 1.f;
        float b0 = fmaxf(fmaxf(cx * cx, cy * cy), fmaxf(cz * cz, cw * cw));
        float dx = vb.x - 1.f, dy = vb.y - 1.f, dz = vb.z - 1.f, dw = vb.w - 1.f;
        float b1 = fmaxf(fmaxf(dx * dx, dy * dy), fmaxf(dz * dz, dw * dw));
        m = fmaxf(fmaxf(a0, a1), fmaxf(b0, b1));
    }
    m = wave_max_bcast(m);
    if (lane == 0) redRow[wid] = m;
    __syncthreads();
    if (t == 0)
        ws[b] = fmaxf(fmaxf(redRow[0], redRow[1]), fmaxf(redRow[2], redRow[3]));

    cg::this_grid().sync();

    // --- global Cmax from 512 row partials (exact max, order-invariant) ---
    float g = fmaxf(ws[t], ws[t + TPB]);
    g = wave_max_bcast(g);
    if (lane == 0) redC[wid] = g;
    __syncthreads();
    const float Cmax = fmaxf(fmaxf(redC[0], redC[1]), fmaxf(redC[2], redC[3]));

    const float kk = C1f * (1.0f / Cmax);
    const float kk2 = 2.0f * kk;

    float q[EPT];
    q[0] = EXP2(fmaf(va.x, kk2, -kk));
    q[1] = EXP2(fmaf(va.y, kk2, -kk));
    q[2] = EXP2(fmaf(va.z, kk2, -kk));
    q[3] = EXP2(fmaf(va.w, kk2, -kk));
    q[4] = EXP2(fmaf(vb.x, kk2, -kk));
    q[5] = EXP2(fmaf(vb.y, kk2, -kk));
    q[6] = EXP2(fmaf(vb.z, kk2, -kk));
    q[7] = EXP2(fmaf(vb.w, kk2, -kk));

    // --- root-find on S(rho)=K.  r = 1/(1+rho q), u = q r:
    //     S = sum r; D = -S' = sum u r; H = S''/2 = sum u^2 r.
    // Guarded Halley: rho + W/(D - (W/D) H) when correction small, else Newton.
    float rho = 0.f, rho_p = -1.f;
    for (int it = 0; it < IT_MAX; ++it) {
        float S0 = 0.f, S1 = 0.f, D0 = 0.f, D1 = 0.f, H0 = 0.f, H1 = 0.f;
#pragma unroll
        for (int i = 0; i < EPT; i += 2) {
            float r0 = RCP(fmaf(rho, q[i], 1.f));
            float r1 = RCP(fmaf(rho, q[i + 1], 1.f));
            float u0 = q[i] * r0;
            float u1 = q[i + 1] * r1;
            S0 += r0;                   S1 += r1;
            D0 = fmaf(u0, r0, D0);      D1 = fmaf(u1, r1, D1);
            H0 = fmaf(u0 * u0, r0, H0); H1 = fmaf(u1 * u1, r1, H1);
        }
        float S = S0 + S1, D = D0 + D1, H = H0 + H1;
        wave_sum3_bcast(S, D, H);
        const int p = it & 1;
        if (lane == 0) { lred[p][0][wid] = S; lred[p][1][wid] = D; lred[p][2][wid] = H; }
        __syncthreads();
        float4 Sv = *(const float4*)lred[p][0];
        float4 Dv = *(const float4*)lred[p][1];
        float4 Hv = *(const float4*)lred[p][2];
        S = (Sv.x + Sv.y) + (Sv.z + Sv.w);
        D = (Dv.x + Dv.y) + (Dv.z + Dv.w);
        H = (Hv.x + Hv.y) + (Hv.z + Hv.w);
        const float W = S - KF;
        const float tN = W * RCP(D);
        const float corr = tN * H;
        const float step = (corr < 0.5f * D) ? W * RCP(D - corr) : tN;
        const float rho_n = rho + step;      // uniform across block
        if (rho_n == rho || rho_n == rho_p) { rho = rho_n; break; }
        rho_p = rho;
        rho = rho_n;
    }

    // --- output: P0 = (1/N) r, P1 = (1/N) rho q r ---
    const float urho = rho * INV_N;
    float4* o0 = (float4*)(out + b * 2 * N);
    float4* o1 = (float4*)(out + b * 2 * N + N);
    float4 r0v, r1v;
    float rp;
    rp = RCP(fmaf(rho, q[0], 1.f)); r0v.x = INV_N * rp; r1v.x = urho * q[0] * rp;
    rp = RCP(fmaf(rho, q[1], 1.f)); r0v.y = INV_N * rp; r1v.y = urho * q[1] * rp;
    rp = RCP(fmaf(rho, q[2], 1.f)); r0v.z = INV_N * rp; r1v.z = urho * q[2] * rp;
    rp = RCP(fmaf(rho, q[3], 1.f)); r0v.w = INV_N * rp; r1v.w = urho * q[3] * rp;
    o0[t] = r0v; o1[t] = r1v;
    rp = RCP(fmaf(rho, q[4], 1.f)); r0v.x = INV_N * rp; r1v.x = urho * q[4] * rp;
    rp = RCP(fmaf(rho, q[5], 1.f)); r0v.y = INV_N * rp; r1v.y = urho * q[5] * rp;
    rp = RCP(fmaf(rho, q[6], 1.f)); r0v.z = INV_N * rp; r1v.z = urho * q[6] * rp;
    rp = RCP(fmaf(rho, q[7], 1.f)); r0v.w = INV_N * rp; r1v.w = urho * q[7] * rp;
    o0[t + TPB] = r0v; o1[t + TPB] = r1v;
}

extern "C" void kernel_launch(void* const* d_in, const int* in_sizes, int n_in,
                              void* d_out, int out_size, void* d_ws, size_t ws_size,
                              hipStream_t stream) {
    const float* scores = (const float*)d_in[0];
    float* out = (float*)d_out;
    float* ws = (float*)d_ws; // 512 floats of row partials; fully rewritten per call

    void* args[] = {(void*)&scores, (void*)&ws, (void*)&out};
    (void)hipLaunchCooperativeKernel((const void*)k_fused, dim3(B), dim3(TPB),
                                     args, 0, stream);
}

// Round 9
// 19.396 us; speedup vs baseline: 3.1218x; 3.1218x over previous
//
#include <hip/hip_runtime.h>

// Sinkhorn top-K — closed-form scalar root-find. Two kernels (cooperative
// grid.sync measured ~35us on MI355X in R8 — cross-XCD flush; reverted).
//   q[n]   = exp2((2 s[n] - 1) * C1f / Cmax)
//   S(rho) = sum_n 1/(1 + rho q[n]) = K    (monotone decreasing, convex)
//   P0[n]  = (1/N)/(1 + rho q[n]);  P1[n] = (1/N) rho q[n]/(1 + rho q[n])
// k_max: 256 partial cost-maxes -> d_ws (every slot stored; no memset).
// k_sink: one block (256 thr) per row; guarded-Halley root-find with
// DPP wave reduce + LDS cross-wave combine; 2-cycle-safe break.

#define EXP2(x) __builtin_amdgcn_exp2f(x)
#define RCP(x)  __builtin_amdgcn_rcpf(x)

constexpr int B = 512;
constexpr int N = 2048;
constexpr int TPB = 256;
constexpr int EPT = N / TPB; // 8 elements per thread
constexpr int IT_MAX = 16;

#define C1f   14.426950408889634f     // log2(e)/EPS
#define KF    512.0f
#define INV_N (1.0f / 2048.0f)

template <int CTRL, int RM>
__device__ __forceinline__ int DPP(int v) {
    return __builtin_amdgcn_update_dpp(0, v, CTRL, RM, 0xf, false);
}

// wave64 max all-reduce (values >= 0) -> uniform in all lanes.
__device__ __forceinline__ float wave_max_bcast(float v) {
    float t;
    t = __int_as_float(DPP<0x111, 0xf>(__float_as_int(v))); v = fmaxf(v, t);
    t = __int_as_float(DPP<0x112, 0xf>(__float_as_int(v))); v = fmaxf(v, t);
    t = __int_as_float(DPP<0x114, 0xf>(__float_as_int(v))); v = fmaxf(v, t);
    t = __int_as_float(DPP<0x118, 0xf>(__float_as_int(v))); v = fmaxf(v, t);
    t = __int_as_float(DPP<0x142, 0xa>(__float_as_int(v))); v = fmaxf(v, t); // row_bcast15
    t = __int_as_float(DPP<0x143, 0xc>(__float_as_int(v))); v = fmaxf(v, t); // row_bcast31
    return __int_as_float(__builtin_amdgcn_readlane(__float_as_int(v), 63));
}

// three interleaved wave64 sum reduces (latency-overlapped DPP chains);
// totals land in lane 63 of each wave.
__device__ __forceinline__ void wave_sum3(float& a, float& b, float& c) {
#define R3(ctrl, rm)                                          \
    {                                                         \
        int ta = DPP<ctrl, rm>(__float_as_int(a));            \
        int tb = DPP<ctrl, rm>(__float_as_int(b));            \
        int tc = DPP<ctrl, rm>(__float_as_int(c));            \
        a += __int_as_float(ta);                              \
        b += __int_as_float(tb);                              \
        c += __int_as_float(tc);                              \
    }
    R3(0x111, 0xf) R3(0x112, 0xf) R3(0x114, 0xf) R3(0x118, 0xf)
    R3(0x142, 0xa) R3(0x143, 0xc)
#undef R3
}

__launch_bounds__(256)
__global__ void k_max(const float* __restrict__ s, float* __restrict__ pmax) {
    __shared__ float red[4];
    const float4* s4 = (const float4*)s;
    const int t = blockIdx.x * 256 + threadIdx.x; // 65536 threads x 4 float4
    float m = 0.f;
#pragma unroll
    for (int j = 0; j < 4; ++j) {
        float4 v = s4[t + j * 65536];
        float a = fmaxf(fmaxf(v.x * v.x, v.y * v.y), fmaxf(v.z * v.z, v.w * v.w));
        float bx = v.x - 1.f, by = v.y - 1.f, bz = v.z - 1.f, bw = v.w - 1.f;
        float bb = fmaxf(fmaxf(bx * bx, by * by), fmaxf(bz * bz, bw * bw));
        m = fmaxf(m, fmaxf(a, bb));
    }
    m = wave_max_bcast(m);
    const int lane = threadIdx.x & 63, wid = threadIdx.x >> 6;
    if (lane == 0) red[wid] = m;
    __syncthreads();
    if (threadIdx.x == 0)
        pmax[blockIdx.x] = fmaxf(fmaxf(red[0], red[1]), fmaxf(red[2], red[3]));
}

__launch_bounds__(TPB)
__global__ void k_sink(const float* __restrict__ scores,
                       const float* __restrict__ pmax,
                       float* __restrict__ out) {
    const int b = blockIdx.x;
    const int t = threadIdx.x;
    const int lane = t & 63, wid = t >> 6;

    __shared__ float redC[4];
    __shared__ alignas(16) float lred[2][3][4]; // [parity][S/D/H][wave]

    // --- row loads first (independent of the pmax reduce) ---
    const float4* src = (const float4*)(scores + b * N);
    float4 va = src[t], vb = src[t + TPB];

    // --- global Cmax from 256 partials: one per thread, block max ---
    float g = wave_max_bcast(pmax[t]);
    if (lane == 0) redC[wid] = g;
    __syncthreads();
    const float Cmax = fmaxf(fmaxf(redC[0], redC[1]), fmaxf(redC[2], redC[3]));

    const float kk = C1f * (1.0f / Cmax);
    const float kk2 = 2.0f * kk;

    float q[EPT];
    q[0] = EXP2(fmaf(va.x, kk2, -kk));
    q[1] = EXP2(fmaf(va.y, kk2, -kk));
    q[2] = EXP2(fmaf(va.z, kk2, -kk));
    q[3] = EXP2(fmaf(va.w, kk2, -kk));
    q[4] = EXP2(fmaf(vb.x, kk2, -kk));
    q[5] = EXP2(fmaf(vb.y, kk2, -kk));
    q[6] = EXP2(fmaf(vb.z, kk2, -kk));
    q[7] = EXP2(fmaf(vb.w, kk2, -kk));

    // --- root-find on S(rho)=K.  r = 1/(1+rho q), u = q r:
    //     S = sum r; D = -S' = sum u r; H = S''/2 = sum u^2 r.
    // Guarded Halley: rho + W/(D - (W/D) H) when correction small, else Newton.
    float rho = 0.f, rho_p = -1.f;
    for (int it = 0; it < IT_MAX; ++it) {
        float S0 = 0.f, S1 = 0.f, D0 = 0.f, D1 = 0.f, H0 = 0.f, H1 = 0.f;
#pragma unroll
        for (int i = 0; i < EPT; i += 2) {
            float r0 = RCP(fmaf(rho, q[i], 1.f));
            float r1 = RCP(fmaf(rho, q[i + 1], 1.f));
            float u0 = q[i] * r0;
            float u1 = q[i + 1] * r1;
            S0 += r0;                   S1 += r1;
            D0 = fmaf(u0, r0, D0);      D1 = fmaf(u1, r1, D1);
            H0 = fmaf(u0 * u0, r0, H0); H1 = fmaf(u1 * u1, r1, H1);
        }
        float S = S0 + S1, D = D0 + D1, H = H0 + H1;
        wave_sum3(S, D, H); // totals in lane 63
        const int p = it & 1;
        if (lane == 63) { lred[p][0][wid] = S; lred[p][1][wid] = D; lred[p][2][wid] = H; }
        __syncthreads();
        float4 Sv = *(const float4*)lred[p][0];
        float4 Dv = *(const float4*)lred[p][1];
        float4 Hv = *(const float4*)lred[p][2];
        S = (Sv.x + Sv.y) + (Sv.z + Sv.w);
        D = (Dv.x + Dv.y) + (Dv.z + Dv.w);
        H = (Hv.x + Hv.y) + (Hv.z + Hv.w);
        const float W = S - KF;
        const float tN = W * RCP(D);
        const float corr = tN * H;
        const float step = (corr < 0.5f * D) ? W * RCP(D - corr) : tN;
        const float rho_n = rho + step;      // uniform across block
        if (rho_n == rho || rho_n == rho_p) { rho = rho_n; break; }
        rho_p = rho;
        rho = rho_n;
    }

    // --- output: P0 = (1/N) r, P1 = (1/N) rho q r ---
    const float urho = rho * INV_N;
    float4* o0 = (float4*)(out + b * 2 * N);
    float4* o1 = (float4*)(out + b * 2 * N + N);
    float4 r0v, r1v;
    float rp;
    rp = RCP(fmaf(rho, q[0], 1.f)); r0v.x = INV_N * rp; r1v.x = urho * q[0] * rp;
    rp = RCP(fmaf(rho, q[1], 1.f)); r0v.y = INV_N * rp; r1v.y = urho * q[1] * rp;
    rp = RCP(fmaf(rho, q[2], 1.f)); r0v.z = INV_N * rp; r1v.z = urho * q[2] * rp;
    rp = RCP(fmaf(rho, q[3], 1.f)); r0v.w = INV_N * rp; r1v.w = urho * q[3] * rp;
    o0[t] = r0v; o1[t] = r1v;
    rp = RCP(fmaf(rho, q[4], 1.f)); r0v.x = INV_N * rp; r1v.x = urho * q[4] * rp;
    rp = RCP(fmaf(rho, q[5], 1.f)); r0v.y = INV_N * rp; r1v.y = urho * q[5] * rp;
    rp = RCP(fmaf(rho, q[6], 1.f)); r0v.z = INV_N * rp; r1v.z = urho * q[6] * rp;
    rp = RCP(fmaf(rho, q[7], 1.f)); r0v.w = INV_N * rp; r1v.w = urho * q[7] * rp;
    o0[t + TPB] = r0v; o1[t + TPB] = r1v;
}

extern "C" void kernel_launch(void* const* d_in, const int* in_sizes, int n_in,
                              void* d_out, int out_size, void* d_ws, size_t ws_size,
                              hipStream_t stream) {
    const float* scores = (const float*)d_in[0];
    float* out = (float*)d_out;
    float* pmax = (float*)d_ws; // 256 floats; fully overwritten by k_max each call

    k_max<<<256, 256, 0, stream>>>(scores, pmax);
    k_sink<<<B, TPB, 0, stream>>>(scores, pmax, out);
}